// Round 12
// baseline (120.562 us; speedup 1.0000x reference)
//
#include <hip/hip_runtime.h>

// Light-field per-pixel 9x9 filter, R12.
// out[b,s,o,h,w] = clip(sum_{i,ky,kx} lf[b,s,i,3h-3+ky,3w-3+kx] * W[s,o,i,h,w,81] + bias, 0, 1)
//
// R11 (100us): 10 small blocks desync'd the staging drains -> only +3%. The
// per-i "issue -> drain -> compute" still exposes each block's stage RTT.
// R12: DOUBLE-BUFFER the weight slices (R4's proven pattern on R11's lean data
// path): barrier -> issue stage(i+1) into buf^1 -> compute(i) from buf. Stage
// latency rides under compute; only the prologue stage is exposed.
// 2 x 15.6 KB = 31.1 KB LDS -> 5 blocks/CU x 4 waves = 20 waves/CU.

#define ST 9
#define INC 3
#define OUTC 3
#define OHH 128
#define OWW 128
#define KDIM 9
#define KK 81
#define HH 384
#define WW 384
#define HWSZ (HH*WW)          // 147456
#define WQ 16                 // w columns per block
#define SLICE (WQ*KK)         // 1296 floats = 5184 B per (s,o,i,h,w-16th)

typedef float f32x4 __attribute__((ext_vector_type(4)));
struct __attribute__((packed, aligned(4))) U4 { f32x4 v; };  // align-4 vector load

__device__ __forceinline__ void gll16(const float* g, float* l) {
  __builtin_amdgcn_global_load_lds((const __attribute__((address_space(1))) void*)g,
                                   (__attribute__((address_space(3))) void*)l, 16, 0, 0);
}

__global__ __launch_bounds__(128) void lf_filter_kernel(
    const float* __restrict__ lf, const float* __restrict__ wts,
    const float* __restrict__ bias, float* __restrict__ out)
{
  __shared__ __align__(16) float ldsW[2][OUTC][SLICE];   // 31104 B -> 5 blocks/CU

  const int t   = threadIdx.x;
  const int wl  = t & 15;          // w within group
  const int b   = (t >> 4) & 3;    // batch
  const int kh  = t >> 6;          // ky half: 0 -> ky 0..4, 1 -> ky 5..8
  const int bid = blockIdx.x;
  const int wg  = bid & 7;         // w group of 16
  const int h   = (bid >> 3) & 127;
  const int s   = bid >> 10;
  const int w   = wg*WQ + wl;
  const int xbase = 3*w - 3;
  const int ybase = 3*h - 3;

  // clamped vector-load base + edge shift (nonzero only for w=0 / w=127)
  const int  base  = xbase < 0 ? 0 : (xbase > WW-KDIM ? WW-KDIM : xbase);
  const bool s_neg = (xbase < base);
  const bool s_pos = (xbase > base);

  const float* lfb = lf + (size_t)(b*ST + s)*INC*HWSZ;
  const int wu = (t & ~63) * 4;    // wave-uniform LDS dest float offset

  const int ky0 = kh ? 5 : 0;
  const int ky1 = kh ? 9 : 5;

  // stage the 3 o-slices of weight-column group for input channel i into buf
  auto stage = [&](int i, int buf) {
    #pragma unroll
    for (int o = 0; o < OUTC; ++o) {
      const float* wsrc = wts + ((size_t)(((s*OUTC + o)*INC + i)*OHH + h)*OWW + wg*WQ)*KK;
      float* dst = ldsW[buf][o];
      #pragma unroll
      for (int j = 0; j < 2; ++j)                      // 256 chunks
        gll16(wsrc + (size_t)(j*128 + t)*4, dst + j*512 + wu);
      if (t < 68)                                      // tail chunks 256..323
        gll16(wsrc + (size_t)(256 + t)*4, dst + 1024 + wu);
    }
  };

  float acc[OUTC] = {0.f, 0.f, 0.f};

  stage(0, 0);

  #pragma unroll 1
  for (int i = 0; i < INC; ++i) {
    __syncthreads();               // drains stage(i); old buffer free
    if (i + 1 < INC) stage(i + 1, (i + 1) & 1);   // in flight under compute(i)

    // ---- compute this thread's ky range; lf row reused across the 3 o's ----
    const float* lfr = lfb + (size_t)i*HWSZ;
    const int wb = wl*KK;
    const float (*wbuf)[SLICE] = ldsW[i & 1];
    #pragma unroll 1
    for (int ky = ky0; ky < ky1; ++ky) {
      const int y = ybase + ky;          // wave-uniform branch
      if ((unsigned)y < (unsigned)HH) {
        const float* rp = lfr + (size_t)y*WW + base;
        const f32x4 va = reinterpret_cast<const U4*>(rp)->v;
        const f32x4 vb = reinterpret_cast<const U4*>(rp + 4)->v;
        const float rc = rp[8];
        const float raw[KDIM] = {va.x, va.y, va.z, va.w, vb.x, vb.y, vb.z, vb.w, rc};
        float lv[KDIM];
        #pragma unroll
        for (int kx = 0; kx < KDIM; ++kx) {
          const float nv = (kx >= 3) ? raw[kx-3] : 0.f;
          const float pv = (kx <= 5) ? raw[kx+3] : 0.f;
          lv[kx] = s_neg ? nv : (s_pos ? pv : raw[kx]);
        }
        #pragma unroll
        for (int o = 0; o < OUTC; ++o) {
          const float* wrow = &wbuf[o][wb + ky*KDIM];   // 17*wl mod 32: conflict-free
          float a = acc[o];
          #pragma unroll
          for (int kx = 0; kx < KDIM; ++kx)
            a = fmaf(lv[kx], wrow[kx], a);
          acc[o] = a;
        }
      }
    }
  }

  // ---- combine ky-halves via LDS (reuse ldsW), then epilogue by kh=0 ----
  float* part = (float*)ldsW;       // 64*3 floats, stride-3: conflict-free
  __syncthreads();                  // everyone done reading weights
  if (kh == 1) {
    const int q = t & 63;
    #pragma unroll
    for (int o = 0; o < OUTC; ++o) part[q*3 + o] = acc[o];
  }
  __syncthreads();
  if (kh == 0) {
    #pragma unroll
    for (int o = 0; o < OUTC; ++o) {
      const float bv = bias[((s*OUTC + o)*OHH + h)*OWW + w];
      float r = acc[o] + part[t*3 + o] + bv;
      r = r < 0.f ? 0.f : (r > 1.f ? 1.f : r);
      out[(((size_t)(b*ST + s)*OUTC + o)*OHH + h)*OWW + w] = r;
    }
  }
}

extern "C" void kernel_launch(void* const* d_in, const int* in_sizes, int n_in,
                              void* d_out, int out_size, void* d_ws, size_t ws_size,
                              hipStream_t stream) {
  const float* lf   = (const float*)d_in[0];
  const float* wts  = (const float*)d_in[1];
  const float* bias = (const float*)d_in[2];
  float* out = (float*)d_out;
  dim3 grid(ST * OHH * 8);   // 9216 blocks: (s, h, w-group)
  dim3 block(128);           // (w:16) x (batch:4) x (ky-half:2)
  hipLaunchKernelGGL(lf_filter_kernel, grid, block, 0, stream, lf, wts, bias, out);
}

// Round 13
// 106.205 us; speedup vs baseline: 1.1352x; 1.1352x over previous
//
#include <hip/hip_runtime.h>

// Light-field per-pixel 9x9 filter, R13.
// out[b,s,o,h,w] = clip(sum_{i,ky,kx} lf[b,s,i,3h-3+ky,3w-3+kx] * W[s,o,i,h,w,81] + bias, 0, 1)
//
// R12 post-mortem: dbuf halved waves/CU (128-thr block = 2 waves; 31KB LDS ->
// 5 blocks/CU = 10 waves) -> regression was occupancy, not dbuf. R13: dbuf at
// CONSTANT occupancy: 256-thr blocks (4 waves) = w:16 x b:4 x ky-quarter:4,
// LDS 2x15.6=31.1KB -> 5 blocks/CU = 20 waves/CU (same as R11) with the per-i
// stage RTT structurally hidden under compute. 4-way partial combine via LDS.

#define ST 9
#define INC 3
#define OUTC 3
#define OHH 128
#define OWW 128
#define KDIM 9
#define KK 81
#define HH 384
#define WW 384
#define HWSZ (HH*WW)          // 147456
#define WQ 16                 // w columns per block
#define SLICE (WQ*KK)         // 1296 floats = 5184 B per (s,o,i,h,w-16th)

typedef float f32x4 __attribute__((ext_vector_type(4)));
struct __attribute__((packed, aligned(4))) U4 { f32x4 v; };  // align-4 vector load

__device__ __forceinline__ void gll16(const float* g, float* l) {
  __builtin_amdgcn_global_load_lds((const __attribute__((address_space(1))) void*)g,
                                   (__attribute__((address_space(3))) void*)l, 16, 0, 0);
}

__global__ __launch_bounds__(256) void lf_filter_kernel(
    const float* __restrict__ lf, const float* __restrict__ wts,
    const float* __restrict__ bias, float* __restrict__ out)
{
  __shared__ __align__(16) float ldsW[2][OUTC][SLICE];   // 31104 B -> 5 blocks/CU

  const int t   = threadIdx.x;
  const int wl  = t & 15;          // w within group
  const int b   = (t >> 4) & 3;    // batch
  const int kq  = t >> 6;          // ky quarter (one wave each)
  const int bid = blockIdx.x;
  const int wg  = bid & 7;         // w group of 16
  const int h   = (bid >> 3) & 127;
  const int s   = bid >> 10;
  const int w   = wg*WQ + wl;
  const int xbase = 3*w - 3;
  const int ybase = 3*h - 3;

  // clamped vector-load base + edge shift (nonzero only for w=0 / w=127)
  const int  base  = xbase < 0 ? 0 : (xbase > WW-KDIM ? WW-KDIM : xbase);
  const bool s_neg = (xbase < base);
  const bool s_pos = (xbase > base);

  const float* lfb = lf + (size_t)(b*ST + s)*INC*HWSZ;
  const int wu = (t & ~63) * 4;    // wave-uniform LDS dest float offset

  const int ky0 = kq*2;
  const int ky1 = (kq == 3) ? 9 : kq*2 + 2;

  // stage the 3 o-slices (324 float4 chunks each) for channel i into buf
  auto stage = [&](int i, int buf) {
    #pragma unroll
    for (int o = 0; o < OUTC; ++o) {
      const float* wsrc = wts + ((size_t)(((s*OUTC + o)*INC + i)*OHH + h)*OWW + wg*WQ)*KK;
      float* dst = ldsW[buf][o];
      gll16(wsrc + (size_t)t*4, dst + wu);             // chunks 0..255
      if (t < 68)                                      // tail chunks 256..323
        gll16(wsrc + (size_t)(256 + t)*4, dst + 1024 + wu);
    }
  };

  float acc[OUTC] = {0.f, 0.f, 0.f};

  stage(0, 0);

  #pragma unroll 1
  for (int i = 0; i < INC; ++i) {
    __syncthreads();               // drains stage(i); old buffer free
    if (i + 1 < INC) stage(i + 1, (i + 1) & 1);   // in flight under compute(i)

    // ---- compute this wave's ky range; lf row reused across the 3 o's ----
    const float* lfr = lfb + (size_t)i*HWSZ;
    const int wb = wl*KK;
    const float (*wbuf)[SLICE] = ldsW[i & 1];
    #pragma unroll 1
    for (int ky = ky0; ky < ky1; ++ky) {
      const int y = ybase + ky;          // wave-uniform branch
      if ((unsigned)y < (unsigned)HH) {
        const float* rp = lfr + (size_t)y*WW + base;
        const f32x4 va = reinterpret_cast<const U4*>(rp)->v;
        const f32x4 vb = reinterpret_cast<const U4*>(rp + 4)->v;
        const float rc = rp[8];
        const float raw[KDIM] = {va.x, va.y, va.z, va.w, vb.x, vb.y, vb.z, vb.w, rc};
        float lv[KDIM];
        #pragma unroll
        for (int kx = 0; kx < KDIM; ++kx) {
          const float nv = (kx >= 3) ? raw[kx-3] : 0.f;
          const float pv = (kx <= 5) ? raw[kx+3] : 0.f;
          lv[kx] = s_neg ? nv : (s_pos ? pv : raw[kx]);
        }
        #pragma unroll
        for (int o = 0; o < OUTC; ++o) {
          const float* wrow = &wbuf[o][wb + ky*KDIM];   // 17*wl mod 32: conflict-free
          float a = acc[o];
          #pragma unroll
          for (int kx = 0; kx < KDIM; ++kx)
            a = fmaf(lv[kx], wrow[kx], a);
          acc[o] = a;
        }
      }
    }
  }

  // ---- combine ky-quarters via LDS (reuse ldsW), epilogue by kq=0 ----
  float* part = (float*)ldsW;       // 3 groups x 64 x 3 floats = 576 floats
  __syncthreads();                  // everyone done reading weights
  if (kq != 0) {
    const int q = t & 63;
    #pragma unroll
    for (int o = 0; o < OUTC; ++o) part[(kq-1)*192 + q*3 + o] = acc[o];
  }
  __syncthreads();
  if (kq == 0) {
    #pragma unroll
    for (int o = 0; o < OUTC; ++o) {
      const float bv = bias[((s*OUTC + o)*OHH + h)*OWW + w];
      float r = acc[o] + part[t*3 + o] + part[192 + t*3 + o] + part[384 + t*3 + o] + bv;
      r = r < 0.f ? 0.f : (r > 1.f ? 1.f : r);
      out[(((size_t)(b*ST + s)*OUTC + o)*OHH + h)*OWW + w] = r;
    }
  }
}

extern "C" void kernel_launch(void* const* d_in, const int* in_sizes, int n_in,
                              void* d_out, int out_size, void* d_ws, size_t ws_size,
                              hipStream_t stream) {
  const float* lf   = (const float*)d_in[0];
  const float* wts  = (const float*)d_in[1];
  const float* bias = (const float*)d_in[2];
  float* out = (float*)d_out;
  dim3 grid(ST * OHH * 8);   // 9216 blocks: (s, h, w-group)
  dim3 block(256);           // (w:16) x (batch:4) x (ky-quarter:4)
  hipLaunchKernelGGL(lf_filter_kernel, grid, block, 0, stream, lf, wts, bias, out);
}